// Round 1
// baseline (544.007 us; speedup 1.0000x reference)
//
#include <hip/hip_runtime.h>

// ChebConv B=4, N=4096, C=128, K=3 fp32.
// Round 5: remove split-K + Cpart round-trip entirely.
//   - gemm_cheb<PHASE>: BM=64 x BN=128 x BK=64 MFMA GEMM, 256 blocks (1/CU),
//     4 waves (1m x 4n, acc 4x2), double-buffered LDS (one barrier/iter),
//     reg-prefetch, granule-XOR swizzle. K=4096 fully accumulated in-register.
//     Epilogue fused: PHASE 0 -> z1 = lr*(deg*x - A@x) - x, writes Zf1 fp32 +
//     z1T bf16 (LDS transpose); PHASE 1 -> z2 = 2*(lr*(deg*z1 - A@z1) - z1) - x.
//   - prep_cast: grid 4x64x4 (1024 blocks, 16 waves/CU) to cover HBM latency.
//   - reduce_z1 / reduce_z2 / mfma_part deleted; Cpart (67 MB traffic) deleted.
// ws: adjB 134.2MB | Zf 16.8MB | xTb 4MB | z1Tb 4MB | deg | Wt

#define NN 4096
#define CF 128
#define NC (NN * CF)
#define LRC 0.9999995f

typedef __attribute__((ext_vector_type(8))) short bf16x8;
typedef __attribute__((ext_vector_type(4))) float f32x4;

__device__ __forceinline__ unsigned short f2b(float f) {
    unsigned u = __float_as_uint(f);
    return (unsigned short)((u + 0x7FFFu + ((u >> 16) & 1u)) >> 16);  // RNE
}

// ---- one fp32 pass over adj: exact degree + bf16 cast ----
// grid (4, 64, 4): 1024 blocks -> 16 waves/CU so loads cover HBM latency.
__global__ __launch_bounds__(256) void prep_cast(const float* __restrict__ adj,
                                                 unsigned short* __restrict__ adjB,
                                                 float* __restrict__ deg) {
    const int b = blockIdx.z;
    const size_t base = (size_t)b * NN * NN;
    const int n0 = blockIdx.x * 1024;
    const int m0 = blockIdx.y * 64;
    const int t = threadIdx.x;
    float4 s = make_float4(0.f, 0.f, 0.f, 0.f);
    const size_t col = (size_t)(n0 + t * 4);
    for (int m = 0; m < 64; ++m) {
        const size_t idx = base + (size_t)(m0 + m) * NN + col;
        const float4 v = *(const float4*)&adj[idx];
        s.x += v.x; s.y += v.y; s.z += v.z; s.w += v.w;
        ushort4 o;
        o.x = f2b(v.x); o.y = f2b(v.y); o.z = f2b(v.z); o.w = f2b(v.w);
        *(ushort4*)&adjB[idx] = o;
    }
    float* dp = deg + b * NN + n0 + t * 4;
    atomicAdd(dp + 0, s.x);
    atomicAdd(dp + 1, s.y);
    atomicAdd(dp + 2, s.z);
    atomicAdd(dp + 3, s.w);
}

// ---- x -> xT bf16 [B][128 feat][4096 node] ----
__global__ __launch_bounds__(256) void transpose_x(const float* __restrict__ x,
                                                   unsigned short* __restrict__ xTb) {
    __shared__ float tile[64][65];
    const int b = blockIdx.z, m0 = blockIdx.x * 64, n0 = blockIdx.y * 64;
    const int t = threadIdx.x;
    const int c = t & 63, r4 = t >> 6;
    const float* xb = x + (size_t)b * NC;
#pragma unroll
    for (int i = 0; i < 16; ++i) {
        int r = i * 4 + r4;
        tile[r][c] = xb[(size_t)(m0 + r) * CF + n0 + c];
    }
    __syncthreads();
    unsigned short* xo = xTb + (size_t)b * NC + (size_t)n0 * NN + m0;
#pragma unroll
    for (int i = 0; i < 16; ++i) {
        int r = i * 4 + r4;
        xo[(size_t)r * NN + c] = f2b(tile[c][r]);
    }
}

__global__ __launch_bounds__(256) void wt_kernel(const float* __restrict__ W,
                                                 float* __restrict__ Wt) {
    const int idx = blockIdx.x * 256 + threadIdx.x;  // < 128*384
    const int o = idx / 384;
    const int f = idx % 384;
    Wt[f * 128 + o] = W[idx];
}

// ---- fused cheb GEMM: acc = adjB[m0..m0+64, :] @ z  (full K=4096), epilogue fused ----
// grid (64, 4), 256 threads = 4 waves, each wave owns 64x32 of the 64x128 output.
template <int PHASE>
__global__ __launch_bounds__(256) void gemm_cheb(
    const unsigned short* __restrict__ adjB,
    const unsigned short* __restrict__ Bt,    // bf16 zT [B][128 feat][4096 node]
    const float* __restrict__ x,
    const float* __restrict__ deg,
    float* __restrict__ Zf,                   // [B][2][4096][128] fp32 (z1, z2)
    unsigned short* __restrict__ z1Tb)        // bf16 z1T, written when PHASE==0
{
    const int t = threadIdx.x;
    const int w = t >> 6, lane = t & 63, q = lane >> 4, l16 = lane & 15;
    const int m0 = blockIdx.x * 64;
    const int b  = blockIdx.y;

    __shared__ __align__(16) short As[2][4096];   // 2 x 8 KB  (64 rows x 64)
    __shared__ __align__(16) short Bs[2][8192];   // 2 x 16 KB (128 rows x 64)

    const int g  = t & 7;          // k-granule (8 shorts = 16 B)
    const int r0 = t >> 3;         // row 0..31

    const unsigned short* ap = adjB + (size_t)b * NN * NN + (size_t)m0 * NN + g * 8;
    const unsigned short* bp = Bt   + (size_t)b * NC + g * 8;

    f32x4 acc[4][2];
#pragma unroll
    for (int i = 0; i < 4; ++i)
#pragma unroll
        for (int j = 0; j < 2; ++j) acc[i][j] = (f32x4)0.f;

    bf16x8 ar[2], br[4];
    ar[0] = *(const bf16x8*)(ap + (size_t)r0 * NN);
    ar[1] = *(const bf16x8*)(ap + (size_t)(r0 + 32) * NN);
#pragma unroll
    for (int i = 0; i < 4; ++i)
        br[i] = *(const bf16x8*)(bp + (size_t)(r0 + 32 * i) * NN);

    // stage tile 0 into buffer 0
    {
        const int ra = r0, rb = r0 + 32;
        *(bf16x8*)&As[0][ra * 64 + ((g ^ (ra & 7)) << 3)] = ar[0];
        *(bf16x8*)&As[0][rb * 64 + ((g ^ (rb & 7)) << 3)] = ar[1];
#pragma unroll
        for (int i = 0; i < 4; ++i) {
            const int r = r0 + 32 * i;
            *(bf16x8*)&Bs[0][r * 64 + ((g ^ (r & 7)) << 3)] = br[i];
        }
    }

    int cur = 0;
    for (int it = 0; it < 64; ++it) {
        __syncthreads();   // buf[cur] visible; all waves done reading buf[cur^1]
        if (it < 63) {
            const size_t kof = (size_t)(it + 1) * 64;
            ar[0] = *(const bf16x8*)(ap + (size_t)r0 * NN + kof);
            ar[1] = *(const bf16x8*)(ap + (size_t)(r0 + 32) * NN + kof);
#pragma unroll
            for (int i = 0; i < 4; ++i)
                br[i] = *(const bf16x8*)(bp + (size_t)(r0 + 32 * i) * NN + kof);
        }
#pragma unroll
        for (int kh = 0; kh < 2; ++kh) {
            bf16x8 af[4], bfr[2];
#pragma unroll
            for (int i = 0; i < 4; ++i) {
                const int ml = i * 16 + l16;
                af[i] = *(const bf16x8*)&As[cur][ml * 64 + ((((kh << 2) + q) ^ (ml & 7)) << 3)];
            }
#pragma unroll
            for (int j = 0; j < 2; ++j) {
                const int nl = w * 32 + j * 16 + l16;
                bfr[j] = *(const bf16x8*)&Bs[cur][nl * 64 + ((((kh << 2) + q) ^ (nl & 7)) << 3)];
            }
#pragma unroll
            for (int i = 0; i < 4; ++i)
#pragma unroll
                for (int j = 0; j < 2; ++j)
                    acc[i][j] = __builtin_amdgcn_mfma_f32_16x16x32_bf16(
                        af[i], bfr[j], acc[i][j], 0, 0, 0);
        }
        if (it < 63) {
            const int nxt = cur ^ 1;
            const int ra = r0, rb = r0 + 32;
            *(bf16x8*)&As[nxt][ra * 64 + ((g ^ (ra & 7)) << 3)] = ar[0];
            *(bf16x8*)&As[nxt][rb * 64 + ((g ^ (rb & 7)) << 3)] = ar[1];
#pragma unroll
            for (int i = 0; i < 4; ++i) {
                const int r = r0 + 32 * i;
                *(bf16x8*)&Bs[nxt][r * 64 + ((g ^ (r & 7)) << 3)] = br[i];
            }
            cur = nxt;
        }
    }

    // ---- fused epilogue ----
    const float* xb   = x + (size_t)b * NC;
    const float* degb = deg + b * NN;
    float* Z1 = Zf + (size_t)b * 2 * NC;

    if (PHASE == 0) {
        __syncthreads();   // done with As/Bs; reuse Bs as transpose staging
        short (*sh)[68] = (short(*)[68])(&Bs[0][0]);   // 128 x 68 shorts = 17 KB
#pragma unroll
        for (int i = 0; i < 4; ++i) {
#pragma unroll
            for (int r = 0; r < 4; ++r) {
                const int ml = i * 16 + q * 4 + r;
                const int m  = m0 + ml;
                const float d = degb[m];
#pragma unroll
                for (int j = 0; j < 2; ++j) {
                    const int n = w * 32 + j * 16 + l16;
                    const float xv = xb[(size_t)m * CF + n];
                    const float zz = LRC * (d * xv - acc[i][j][r]) - xv;
                    Z1[(size_t)m * CF + n] = zz;
                    sh[n][ml] = (short)f2b(zz);
                }
            }
        }
        __syncthreads();
        // thread t writes feature row f = t>>1, half (t&1): 32 nodes = 64 B
        const int f  = t >> 1;
        const int h0 = (t & 1) * 32;
        unsigned short* zo = z1Tb + (size_t)b * NC + (size_t)f * NN + m0 + h0;
        const short* srow = &sh[f][h0];
#pragma unroll
        for (int v = 0; v < 8; ++v)
            ((ushort4*)zo)[v] = ((const ushort4*)srow)[v];
    } else {
        const float* Z1c = Z1;
        float* Z2 = Z1 + NC;
#pragma unroll
        for (int i = 0; i < 4; ++i) {
#pragma unroll
            for (int r = 0; r < 4; ++r) {
                const int m = m0 + i * 16 + q * 4 + r;
                const float d = degb[m];
#pragma unroll
                for (int j = 0; j < 2; ++j) {
                    const int n = w * 32 + j * 16 + l16;
                    const float xv  = xb[(size_t)m * CF + n];
                    const float z1v = Z1c[(size_t)m * CF + n];
                    Z2[(size_t)m * CF + n] =
                        2.f * (LRC * (d * z1v - acc[i][j][r]) - z1v) - xv;
                }
            }
        }
    }
}

// ---- final fp32 GEMM over the TRUE scrambled view ----
// view row m, col f  ->  flat index G = m*384+f over [x | z1 | z2] (each 2^19 elems)
__global__ __launch_bounds__(256) void gemm_final(const float* __restrict__ x,
                                                  const float* __restrict__ Zf,
                                                  const float* __restrict__ Wt,
                                                  float* __restrict__ out) {
    const int b = blockIdx.z;
    float* Cb = out + (size_t)b * NC;

    const int t = threadIdx.x;
    const int tx = t & 15, ty = t >> 4;
    const int m0 = blockIdx.y * 64, n0 = blockIdx.x * 64;

    __shared__ float Asm[16][68];
    __shared__ float Bsm[16][64];

    const int arow = t >> 2;
    const int ak4 = (t & 3) << 2;
    const int bk = t >> 4;
    const int bn4 = (t & 15) << 2;

    const float* xb = x + (size_t)b * NC;

    float4 acc[4];
    acc[0] = acc[1] = acc[2] = acc[3] = make_float4(0.f, 0.f, 0.f, 0.f);

    const float* bptr = Wt + (size_t)bk * 128 + n0 + bn4;

    auto aload = [&](int k) -> float4 {
        const unsigned G = (unsigned)(m0 + arow) * 384u + (unsigned)k;
        const int chunk = (int)(G >> 19);
        const unsigned rem = G & 524287u;
        const float* src = (chunk == 0) ? xb : (Zf + (size_t)(b * 2 + (chunk - 1)) * NC);
        return *(const float4*)&src[rem];
    };

    float4 av = aload(ak4);
    float4 bv = *(const float4*)bptr;

    for (int k0 = 0; k0 < 384; k0 += 16) {
        __syncthreads();
        Asm[ak4 + 0][arow] = av.x;
        Asm[ak4 + 1][arow] = av.y;
        Asm[ak4 + 2][arow] = av.z;
        Asm[ak4 + 3][arow] = av.w;
        *(float4*)&Bsm[bk][bn4] = bv;
        __syncthreads();
        if (k0 + 16 < 384) {
            av = aload(k0 + 16 + ak4);
            bv = *(const float4*)(bptr + (size_t)(k0 + 16) * 128);
        }
#pragma unroll
        for (int kk = 0; kk < 16; ++kk) {
            const float4 a = *(const float4*)&Asm[kk][ty << 2];
            const float4 bb = *(const float4*)&Bsm[kk][tx << 2];
            acc[0].x += a.x * bb.x; acc[0].y += a.x * bb.y; acc[0].z += a.x * bb.z; acc[0].w += a.x * bb.w;
            acc[1].x += a.y * bb.x; acc[1].y += a.y * bb.y; acc[1].z += a.y * bb.z; acc[1].w += a.y * bb.w;
            acc[2].x += a.z * bb.x; acc[2].y += a.z * bb.y; acc[2].z += a.z * bb.z; acc[2].w += a.z * bb.w;
            acc[3].x += a.w * bb.x; acc[3].y += a.w * bb.y; acc[3].z += a.w * bb.z; acc[3].w += a.w * bb.w;
        }
    }

    const int ncol = n0 + (tx << 2);
#pragma unroll
    for (int i = 0; i < 4; ++i) {
        const int m = m0 + (ty << 2) + i;
        *(float4*)&Cb[(size_t)m * 128 + ncol] = acc[i];
    }
}

extern "C" void kernel_launch(void* const* d_in, const int* in_sizes, int n_in,
                              void* d_out, int out_size, void* d_ws, size_t ws_size,
                              hipStream_t stream) {
    const float* x   = (const float*)d_in[0];   // [4, 4096, 128]
    const float* adj = (const float*)d_in[1];   // [4, 4096, 4096]
    const float* W   = (const float*)d_in[2];   // [128, 384]
    float* out = (float*)d_out;

    char* ws = (char*)d_ws;
    unsigned short* adjB = (unsigned short*)ws;                     // 134,217,728 B
    float* Zf            = (float*)(ws + 134217728u);               //  16,777,216 B  [b][z1,z2][4096][128]
    unsigned short* xTb  = (unsigned short*)(ws + 150994944u);      //   4,194,304 B
    unsigned short* z1Tb = (unsigned short*)(ws + 155189248u);      //   4,194,304 B
    float* deg           = (float*)(ws + 159383552u);               //      65,536 B
    float* Wt            = (float*)(ws + 159449088u);               //     196,608 B

    hipMemsetAsync(deg, 0, 4 * NN * sizeof(float), stream);
    prep_cast<<<dim3(4, 64, 4), 256, 0, stream>>>(adj, adjB, deg);
    transpose_x<<<dim3(64, 2, 4), 256, 0, stream>>>(x, xTb);
    wt_kernel<<<192, 256, 0, stream>>>(W, Wt);

    // Z1 = lr*(deg*x - adj@x) - x   (epilogue fused, also emits z1T bf16)
    gemm_cheb<0><<<dim3(64, 4), 256, 0, stream>>>(adjB, xTb, x, deg, Zf, z1Tb);
    // Z2 = 2*(lr*(deg*z1 - adj@z1) - z1) - x
    gemm_cheb<1><<<dim3(64, 4), 256, 0, stream>>>(adjB, z1Tb, x, deg, Zf, z1Tb);

    // out = [x | z1 | z2] (scrambled view) @ Wt
    gemm_final<<<dim3(2, 64, 4), 256, 0, stream>>>(x, Zf, Wt, out);
}